// Round 8
// baseline (594.219 us; speedup 1.0000x reference)
//
#include <hip/hip_runtime.h>

#define NF 128
#define NH 128
#define NO 256
#define NG 256

typedef unsigned int   u32;
typedef unsigned short u16;
typedef __attribute__((ext_vector_type(8))) short short8;
typedef __attribute__((ext_vector_type(4))) float floatx4;

__device__ __forceinline__ float bflo(u32 g) { return __uint_as_float(g << 16); }
__device__ __forceinline__ float bfhi(u32 g) { return __uint_as_float(g & 0xffff0000u); }
__device__ __forceinline__ u16 f2bf(float x) {
    u32 u = __float_as_uint(x);
    u += 0x7fffu + ((u >> 16) & 1u);
    return (u16)(u >> 16);
}
__device__ __forceinline__ u32 packbf2(float x, float y) {
    u32 ux = __float_as_uint(x); ux += 0x7fffu + ((ux >> 16) & 1u);
    u32 uy = __float_as_uint(y); uy += 0x7fffu + ((uy >> 16) & 1u);
    return (ux >> 16) | (uy & 0xffff0000u);
}

// ---------------- degree histogram ----------------

__global__ void hist_kernel(const int* __restrict__ col, int E, int* __restrict__ deg) {
    int e = blockIdx.x * blockDim.x + threadIdx.x;
    if (e < E) atomicAdd(&deg[col[e]], 1);
}

// ---------------- scan (+dinv fused) ----------------

__global__ void scan1(const int* __restrict__ deg, int n, int* __restrict__ offs,
                      int* __restrict__ partials, float* __restrict__ dinv) {
    __shared__ int sh[256];
    int tid = threadIdx.x;
    int i = blockIdx.x * 256 + tid;
    int v = (i < n) ? deg[i] : 0;
    if (i < n) dinv[i] = rsqrtf((float)v + 1.0f);
    sh[tid] = v; __syncthreads();
    for (int d = 1; d < 256; d <<= 1) {
        int t = (tid >= d) ? sh[tid - d] : 0;
        __syncthreads();
        sh[tid] += t;
        __syncthreads();
    }
    if (i < n) offs[i] = sh[tid] - v;
    if (tid == 255) partials[blockIdx.x] = sh[255];
}

__global__ void scan2(int* __restrict__ partials, int nb) {
    __shared__ int sh[512];
    int tid = threadIdx.x;
    int v = (tid < nb) ? partials[tid] : 0;
    sh[tid] = v; __syncthreads();
    for (int d = 1; d < 512; d <<= 1) {
        int t = (tid >= d) ? sh[tid - d] : 0;
        __syncthreads();
        sh[tid] += t;
        __syncthreads();
    }
    if (tid < nb) partials[tid] = sh[tid] - v;
}

// finalize offs; also init coarse-bucket global cursors gcur[b] = offs[b*512]
__global__ void scan3_gcur(int* __restrict__ offs, const int* __restrict__ partials,
                           int* __restrict__ gcur, int n) {
    int i = blockIdx.x * blockDim.x + threadIdx.x;
    if (i < n) {
        int v = offs[i] + partials[i >> 8];
        offs[i] = v;
        if ((i & 511) == 0) gcur[i >> 9] = v;
    }
}

// ---------------- phase 1: coarse binning (bucket = col >> 9) ----------------
// packed record: row (17 bits) | (col & 511) << 17

__global__ __launch_bounds__(256) void bin_coarse(const int* __restrict__ row,
                                                  const int* __restrict__ col,
                                                  int* __restrict__ gcur,
                                                  u32* __restrict__ coarse, int E) {
    __shared__ u32 cnt[256];
    __shared__ u32 lcur[256];
    __shared__ u32 gbase[256];
    __shared__ u32 sc[256];
    __shared__ u32 packed[4096];
    int t = threadIdx.x;
    int base = blockIdx.x * 4096;
    cnt[t] = 0;
    __syncthreads();

    u32 rv[16], cv[16];
    #pragma unroll
    for (int i = 0; i < 16; ++i) {
        int e = base + i * 256 + t;
        if (e < E) {
            rv[i] = (u32)row[e];
            cv[i] = (u32)col[e];
            atomicAdd(&cnt[cv[i] >> 9], 1u);
        }
    }
    __syncthreads();
    u32 own = cnt[t];
    sc[t] = own; __syncthreads();
    for (int d = 1; d < 256; d <<= 1) {
        u32 x = (t >= d) ? sc[t - d] : 0;
        __syncthreads();
        sc[t] += x;
        __syncthreads();
    }
    u32 excl = sc[t] - own;
    u32 total = sc[255];
    if (own > 0) gbase[t] = (u32)atomicAdd(&gcur[t], (int)own);
    cnt[t]  = excl;
    lcur[t] = excl;
    __syncthreads();

    #pragma unroll
    for (int i = 0; i < 16; ++i) {
        int e = base + i * 256 + t;
        if (e < E) {
            u32 p = atomicAdd(&lcur[cv[i] >> 9], 1u);
            packed[p] = rv[i] | ((cv[i] & 511u) << 17);
        }
    }
    __syncthreads();

    for (u32 i = t; i < total; i += 256) {
        u32 lo = 0, hi = 255;
        while (lo < hi) { u32 mid = (lo + hi + 1) >> 1; if (cnt[mid] <= i) lo = mid; else hi = mid - 1; }
        coarse[gbase[lo] + (i - cnt[lo])] = packed[i];
    }
}

// ---------------- phase 2: fine scatter, segments grouped by src-block ----------------
// one WG per 512-dst bucket; stage window in LDS; npass sequential passes over
// src ranges of 16384 nodes (4 MB of g-table) so each CSR segment ends up
// src-block-sorted -> concurrent waves in gcn_aggregate share L2 working set.

__global__ __launch_bounds__(256) void scatter_fine(const u32* __restrict__ coarse,
                                                    const int* __restrict__ offs,
                                                    int* __restrict__ cursor,
                                                    u32* __restrict__ srcs,
                                                    int N, int E, int npass) {
    __shared__ u32 buf[10240];
    int b = blockIdx.x;
    int lo_node = b << 9;
    if (lo_node >= N) return;
    int hi_node = min(lo_node + 512, N);
    int start = offs[lo_node];
    int end   = (hi_node < N) ? offs[hi_node] : E;

    for (int cbase = start; cbase < end; cbase += 10240) {
        int cnt = min(cbase + 10240, end) - cbase;
        for (int i = threadIdx.x; i < cnt; i += 256) buf[i] = coarse[cbase + i];
        __syncthreads();
        for (int p = 0; p < npass; ++p) {
            for (int i = threadIdx.x; i < cnt; i += 256) {
                u32 pk = buf[i];
                u32 r = pk & 0x1ffffu;
                if ((int)(r >> 14) == p) {
                    u32 c = (u32)lo_node + (pk >> 17);
                    int pos = offs[c] + atomicAdd(&cursor[c], 1);
                    srcs[pos] = r;
                }
            }
            __syncthreads();   // pass p fully placed before pass p+1 claims slots
        }
    }
}

// ---------------- casts ----------------

__global__ void cast_x_kernel(const float* __restrict__ x, u16* __restrict__ xb, long total4) {
    long i = (long)blockIdx.x * 256 + threadIdx.x;
    if (i < total4) {
        float4 v = ((const float4*)x)[i];
        ushort4 o; o.x = f2bf(v.x); o.y = f2bf(v.y); o.z = f2bf(v.z); o.w = f2bf(v.w);
        ((ushort4*)xb)[i] = o;
    }
}

__global__ void cast_w_t3(const float* __restrict__ W1, const float* __restrict__ W2,
                          const float* __restrict__ W3, u16* __restrict__ Wt1,
                          u16* __restrict__ Wt2, u16* __restrict__ Wt3) {
    int idx = blockIdx.x * 256 + threadIdx.x;
    int w = idx >> 14;
    int r = idx & 16383;
    const float* W = (w == 0) ? W1 : (w == 1) ? W2 : W3;
    u16* Wt = (w == 0) ? Wt1 : (w == 1) ? Wt2 : Wt3;
    int k = r >> 7, c = r & 127;
    Wt[c * NF + k] = f2bf(W[r]);
}

// ---------------- MFMA GEMM + dinv row-scale epilogue ----------------
// writes g[node] = dinv[node] * (A[node] @ W)  (bf16)

__global__ __launch_bounds__(256) void gemm_mfma(const u16* __restrict__ A,
                                                 const u16* __restrict__ Wtg,
                                                 const float* __restrict__ dinv,
                                                 u16* __restrict__ C, int n) {
    __shared__ u16 As[64 * 136];
    __shared__ u16 Wt[128 * 136];
    int t = threadIdx.x;
    int node0 = blockIdx.x * 64;

    const uint4* Ag = (const uint4*)A;
    #pragma unroll
    for (int i = 0; i < 4; ++i) {
        int idx = t + 256 * i;
        int nd = idx >> 4, q = idx & 15;
        uint4 v = make_uint4(0, 0, 0, 0);
        if (node0 + nd < n) v = Ag[(size_t)(node0 + nd) * 16 + q];
        *(uint4*)&As[nd * 136 + q * 8] = v;
    }
    const uint4* Wg = (const uint4*)Wtg;
    #pragma unroll
    for (int i = 0; i < 8; ++i) {
        int idx = t + 256 * i;
        int cc = idx >> 4, q = idx & 15;
        *(uint4*)&Wt[cc * 136 + q * 8] = Wg[cc * 16 + q];
    }
    __syncthreads();

    int wv = t >> 6;
    int l  = t & 63;
    int lr = l & 15;
    int lq = l >> 4;

    floatx4 acc[8];
    #pragma unroll
    for (int c = 0; c < 8; ++c) acc[c] = (floatx4){0.f, 0.f, 0.f, 0.f};

    #pragma unroll
    for (int kk = 0; kk < 4; ++kk) {
        short8 af = *(const short8*)&As[(wv * 16 + lr) * 136 + kk * 32 + lq * 8];
        #pragma unroll
        for (int c = 0; c < 8; ++c) {
            short8 bf = *(const short8*)&Wt[(c * 16 + lr) * 136 + kk * 32 + lq * 8];
            acc[c] = __builtin_amdgcn_mfma_f32_16x16x32_bf16(af, bf, acc[c], 0, 0, 0);
        }
    }
    __syncthreads();

    float* Cs = (float*)Wt;   // 64 x 132 f32
    #pragma unroll
    for (int c = 0; c < 8; ++c)
        #pragma unroll
        for (int r = 0; r < 4; ++r)
            Cs[(wv * 16 + lq * 4 + r) * 132 + c * 16 + lr] = acc[c][r];
    __syncthreads();

    int nd = t >> 2, seg = t & 3;
    if (node0 + nd < n) {
        float di = dinv[node0 + nd];
        const float* src = &Cs[nd * 132 + seg * 32];
        u32 o[16];
        #pragma unroll
        for (int i = 0; i < 16; ++i) o[i] = packbf2(di * src[2 * i], di * src[2 * i + 1]);
        uint4* dst = (uint4*)(C + (size_t)(node0 + nd) * NH + seg * 32);
        dst[0] = make_uint4(o[0],  o[1],  o[2],  o[3]);
        dst[1] = make_uint4(o[4],  o[5],  o[6],  o[7]);
        dst[2] = make_uint4(o[8],  o[9],  o[10], o[11]);
        dst[3] = make_uint4(o[12], o[13], o[14], o[15]);
    }
}

// ---------------- fused aggregate: out = relu(dinv*(sum g[src] + g[self]) + b) ----------------

__global__ __launch_bounds__(256) void gcn_aggregate(const u16* __restrict__ gtab,
                                                     const u32* __restrict__ srcs,
                                                     const int* __restrict__ offs,
                                                     const int* __restrict__ deg,
                                                     const float* __restrict__ dinv,
                                                     const float* __restrict__ bias,
                                                     u16* __restrict__ outb, int n) {
    int wv = threadIdx.x >> 6;
    int l  = threadIdx.x & 63;
    int node = blockIdx.x * 4 + wv;
    if (node >= n) return;
    int start = offs[node];
    int end   = start + deg[node];
    const u32* rows = (const u32*)gtab;

    float a0 = 0.f, a1 = 0.f;
    int k = start;
    for (; k + 16 <= end; k += 16) {
        u32 gv[16];
        #pragma unroll
        for (int i = 0; i < 16; ++i) {
            u32 s = srcs[k + i];
            gv[i] = rows[(size_t)s * 64 + l];
        }
        #pragma unroll
        for (int i = 0; i < 16; ++i) { a0 += bflo(gv[i]); a1 += bfhi(gv[i]); }
    }
    for (; k + 4 <= end; k += 4) {
        u32 s0 = srcs[k], s1 = srcs[k + 1], s2 = srcs[k + 2], s3 = srcs[k + 3];
        u32 g0 = rows[(size_t)s0 * 64 + l];
        u32 g1 = rows[(size_t)s1 * 64 + l];
        u32 g2 = rows[(size_t)s2 * 64 + l];
        u32 g3 = rows[(size_t)s3 * 64 + l];
        a0 += bflo(g0) + bflo(g1) + bflo(g2) + bflo(g3);
        a1 += bfhi(g0) + bfhi(g1) + bfhi(g2) + bfhi(g3);
    }
    for (; k < end; ++k) {
        u32 g = rows[(size_t)srcs[k] * 64 + l];
        a0 += bflo(g); a1 += bfhi(g);
    }
    u32 gs = rows[(size_t)node * 64 + l];
    a0 += bflo(gs); a1 += bfhi(gs);
    float di = dinv[node];
    float2 bb = *(const float2*)&bias[l * 2];
    a0 = fmaxf(di * a0 + bb.x, 0.f);
    a1 = fmaxf(di * a1 + bb.y, 0.f);
    ((u32*)outb)[(size_t)node * 64 + l] = packbf2(a0, a1);
}

// ---------------- fused mean-pool + final FC ----------------

__global__ __launch_bounds__(256) void pool_fc(const u16* __restrict__ h,
                                               const int* __restrict__ batch,
                                               const float* __restrict__ Wfc,
                                               const float* __restrict__ bfc,
                                               float* __restrict__ out, int n) {
    int g = blockIdx.x;
    int tid = threadIdx.x;
    int j = tid & 127;
    int half = tid >> 7;

    int lo = 0, hi = n;
    while (lo < hi) { int m = (lo + hi) >> 1; if (batch[m] < g) lo = m + 1; else hi = m; }
    int start = lo;
    hi = n;
    while (lo < hi) { int m = (lo + hi) >> 1; if (batch[m] < g + 1) lo = m + 1; else hi = m; }
    int end = lo;

    float a0 = 0.f, a1 = 0.f, a2 = 0.f, a3 = 0.f;
    int i = start + half;
    for (; i + 6 < end; i += 8) {
        u32 v0 = (u32)h[(size_t)i * NH + j];
        u32 v1 = (u32)h[(size_t)(i + 2) * NH + j];
        u32 v2 = (u32)h[(size_t)(i + 4) * NH + j];
        u32 v3 = (u32)h[(size_t)(i + 6) * NH + j];
        a0 += __uint_as_float(v0 << 16);
        a1 += __uint_as_float(v1 << 16);
        a2 += __uint_as_float(v2 << 16);
        a3 += __uint_as_float(v3 << 16);
    }
    for (; i < end; i += 2)
        a0 += __uint_as_float((u32)h[(size_t)i * NH + j] << 16);
    float acc = (a0 + a1) + (a2 + a3);

    __shared__ float sum[NH];
    __shared__ float pr[NH];
    if (half == 0) sum[j] = acc;
    __syncthreads();
    if (half == 1) sum[j] += acc;
    __syncthreads();
    float inv = 1.0f / fmaxf((float)(end - start), 1.0f);
    if (half == 0) pr[j] = sum[j] * inv;
    __syncthreads();

    float o = bfc[tid];
    #pragma unroll 8
    for (int k = 0; k < NH; ++k) o += pr[k] * Wfc[(size_t)k * NO + tid];
    out[(size_t)g * NO + tid] = o;
}

// ---------------- launch ----------------

extern "C" void kernel_launch(void* const* d_in, const int* in_sizes, int n_in,
                              void* d_out, int out_size, void* d_ws, size_t ws_size,
                              hipStream_t stream) {
    const float* x   = (const float*)d_in[0];
    const float* W1  = (const float*)d_in[1];
    const float* b1  = (const float*)d_in[2];
    const float* W2  = (const float*)d_in[3];
    const float* b2  = (const float*)d_in[4];
    const float* W3  = (const float*)d_in[5];
    const float* b3  = (const float*)d_in[6];
    const float* Wfc = (const float*)d_in[7];
    const float* bfc = (const float*)d_in[8];
    const int*   ei  = (const int*)d_in[9];
    const int*   bat = (const int*)d_in[10];
    float* out = (float*)d_out;

    const int N = in_sizes[0] / NF;
    const int E = in_sizes[9] / 2;
    const int* rowp = ei;
    const int* colp = ei + E;

    // workspace layout
    char* w = (char*)d_ws;
    u32* srcs    = (u32*)w;                      w += (size_t)E * 4;
    u32* coarse  = (u32*)w;                      w += (size_t)E * 4;
    u16* hA   = (u16*)w;                         w += (size_t)N * NH * 2;
    u16* hB   = (u16*)w;                         w += (size_t)N * NH * 2;
    u16* tmpb = (u16*)w;                         w += (size_t)N * NH * 2;
    u16* Wt1  = (u16*)w;                         w += NF * NH * 2;
    u16* Wt2  = (u16*)w;                         w += NF * NH * 2;
    u16* Wt3  = (u16*)w;                         w += NF * NH * 2;
    float* dinv = (float*)w;                     w += (size_t)N * 4;
    int* degc   = (int*)w;                       w += (size_t)N * 4;
    int* cursor = (int*)w;                       w += (size_t)N * 4;   // adjacent to degc (one memset)
    int* offs   = (int*)w;                       w += (size_t)N * 4;
    int* partials = (int*)w;                     w += 512 * 4;
    int* gcur   = (int*)w;                       w += 256 * 4;

    const int TB = 256;
    int gE = (E + TB - 1) / TB;
    int gN = (N + TB - 1) / TB;
    int gGemm = (N + 63) / 64;
    int gAgg  = (N + 3) / 4;
    int nScanBlocks = (N + 255) / 256;   // <= 512
    int NB = (N + 511) >> 9;             // coarse buckets (<=256)
    int gBin = (E + 4095) / 4096;
    int nPass = (N + 16383) >> 14;       // src ranges of 16K nodes (4MB g-table)

    // ---- CSR build ----
    hipMemsetAsync(degc, 0, 2 * (size_t)N * sizeof(int), stream);   // degc + cursor
    hist_kernel<<<gE, TB, 0, stream>>>(colp, E, degc);
    scan1<<<nScanBlocks, 256, 0, stream>>>(degc, N, offs, partials, dinv);
    scan2<<<1, 512, 0, stream>>>(partials, nScanBlocks);
    scan3_gcur<<<gN, TB, 0, stream>>>(offs, partials, gcur, N);
    bin_coarse<<<gBin, TB, 0, stream>>>(rowp, colp, gcur, coarse, E);
    scatter_fine<<<NB, TB, 0, stream>>>(coarse, offs, cursor, srcs, N, E, nPass);

    // ---- casts ----
    long total4 = (long)N * NF / 4;
    cast_x_kernel<<<(int)((total4 + 255) / 256), TB, 0, stream>>>(x, hA, total4);
    cast_w_t3<<<192, TB, 0, stream>>>(W1, W2, W3, Wt1, Wt2, Wt3);

    // ---- layer 1 ----
    gemm_mfma<<<gGemm, TB, 0, stream>>>(hA, Wt1, dinv, tmpb, N);
    gcn_aggregate<<<gAgg, TB, 0, stream>>>(tmpb, srcs, offs, degc, dinv, b1, hB, N);

    // ---- layer 2 ----
    gemm_mfma<<<gGemm, TB, 0, stream>>>(hB, Wt2, dinv, tmpb, N);
    gcn_aggregate<<<gAgg, TB, 0, stream>>>(tmpb, srcs, offs, degc, dinv, b2, hA, N);

    // ---- layer 3 ----
    gemm_mfma<<<gGemm, TB, 0, stream>>>(hA, Wt3, dinv, tmpb, N);
    gcn_aggregate<<<gAgg, TB, 0, stream>>>(tmpb, srcs, offs, degc, dinv, b3, hB, N);

    // ---- fused pool + fc ----
    pool_fc<<<NG, 256, 0, stream>>>(hB, bat, Wfc, bfc, out, N);
}